// Round 7
// baseline (617.768 us; speedup 1.0000x reference)
//
#include <hip/hip_runtime.h>
#include <hip/hip_fp16.h>
#include <math.h>

#define N_NODES 50000
#define MP      50048              /* padded rows = 391*128 */
#define N_EDGES 800000
#define E_TOT   (N_EDGES + N_NODES)
#define HEADS   4
#define CH      128
#define NOUT    512
#define NEG_SLOPE 0.2f

typedef unsigned int u32;
typedef unsigned short u16;
typedef __attribute__((ext_vector_type(8))) _Float16 f16x8;
typedef __attribute__((ext_vector_type(4))) float f32x4;

// ---------------- CSR build ----------------

__global__ __launch_bounds__(256) void count_deg(const int* __restrict__ ei,
                                                 int* __restrict__ deg) {
  int e = blockIdx.x * 256 + threadIdx.x;
  if (e >= E_TOT) return;
  int dst = (e < N_EDGES) ? ei[N_EDGES + e] : (e - N_EDGES);
  atomicAdd(&deg[dst], 1);
}

// single block, 1024 threads: per-thread sequential chunk + one 1024-wide scan
__global__ __launch_bounds__(1024) void scan_deg_fast(const int* __restrict__ deg,
                                                      int* __restrict__ row_ptr) {
  __shared__ int ssum[1024];
  const int tid = threadIdx.x;
  const int CHUNK = (N_NODES + 1023) / 1024;   // 49
  const int base = tid * CHUNK;
  int s = 0;
  for (int i = 0; i < CHUNK; ++i) {
    int idx = base + i;
    if (idx < N_NODES) s += deg[idx];
  }
  ssum[tid] = s;
  __syncthreads();
  for (int off = 1; off < 1024; off <<= 1) {
    int v = (tid >= off) ? ssum[tid - off] : 0;
    __syncthreads();
    ssum[tid] += v;
    __syncthreads();
  }
  int run = (tid > 0) ? ssum[tid - 1] : 0;
  for (int i = 0; i < CHUNK; ++i) {
    int idx = base + i;
    if (idx < N_NODES) { run += deg[idx]; row_ptr[idx + 1] = run; }
  }
  if (tid == 0) row_ptr[0] = 0;
}

__global__ __launch_bounds__(256) void scatter_edges(const int* __restrict__ ei,
                                                     const int* __restrict__ row_ptr,
                                                     int* __restrict__ cursor,
                                                     int* __restrict__ col) {
  int e = blockIdx.x * 256 + threadIdx.x;
  if (e >= E_TOT) return;
  int src, dst;
  if (e < N_EDGES) { src = ei[e]; dst = ei[N_EDGES + e]; }
  else             { src = e - N_EDGES; dst = src; }
  int pos = atomicAdd(&cursor[dst], 1);
  col[row_ptr[dst] + pos] = src;
}

// ---------------- combined fp32 -> fp16 cast: x, W1, W2 ----------------

#define CVT_N0 (N_NODES * 256 / 4)        /* 3,200,000 float4 for x  */
#define CVT_N1 (CVT_N0 + 512 * 256 / 4)   /* + 32768 for W1 */
#define CVT_N2 (CVT_N1 + 512 * 128 / 4)   /* + 16384 for W2 */

__global__ __launch_bounds__(256) void cvt_all_f16(
    const float* __restrict__ x,  __half* __restrict__ A16,
    const float* __restrict__ W1, __half* __restrict__ B1,
    const float* __restrict__ W2, __half* __restrict__ B2) {
  int i = blockIdx.x * 256 + threadIdx.x;
  const float* s; __half* d; int k;
  if (i < CVT_N0)      { s = x;  d = A16; k = i; }
  else if (i < CVT_N1) { s = W1; d = B1;  k = i - CVT_N0; }
  else if (i < CVT_N2) { s = W2; d = B2;  k = i - CVT_N1; }
  else return;
  float4 v = ((const float4*)s)[k];
  __half2 h01 = __float22half2_rn(make_float2(v.x, v.y));
  __half2 h23 = __float22half2_rn(make_float2(v.z, v.w));
  uint2 pk = make_uint2(*(u32*)&h01, *(u32*)&h23);
  ((uint2*)d)[k] = pk;
}

// ---------------- fp16 MFMA GEMM + fused attention epilogue ----------------
// C_fp16[MP,512] = A_fp16[M,K] @ B_fp16[512,K]^T, fp32 accumulate.
// Grid (MP/128, 4): block = 128 rows x 128 cols; col-block == head hb.
// K-loop: DOUBLE-BUFFERED LDS (BK=32, 2x16KB planes): iter i stages tile i+1
// async (global_load_lds w16) into buf[(i+1)&1] while computing from buf[i&1];
// ONE barrier per step — the vmcnt drain overlaps the MFMA+ds_read of the
// current tile (the r6 two-barrier loop was staging-latency-bound).
// Epilogue: per-row <xh,att_s/d> from fp32 accs (replaces node_att).

#define GLD16(gp, lp)                                                          \
  __builtin_amdgcn_global_load_lds(                                            \
      (const __attribute__((address_space(1))) u32*)(gp),                      \
      (__attribute__((address_space(3))) u32*)(lp), 16, 0, 0)

template <int K>
__global__ __launch_bounds__(256) void gemm_att(
    const __half* __restrict__ A, const __half* __restrict__ B,
    const float* __restrict__ att_s, const float* __restrict__ att_d,
    __half* __restrict__ C, float* __restrict__ as_, float* __restrict__ ad_) {
  __shared__ u16 sA[2][128 * 32];    // 8 KB per buffer, row*32 + k
  __shared__ u16 sB[2][128 * 32];
  __shared__ float sAtt[2][4][64];
  const int tid  = threadIdx.x;
  const int lane = tid & 63;
  const int wave = tid >> 6;
  const int m0 = blockIdx.x * 128;
  const int hb = blockIdx.y;
  const int n0 = hb * 128;
  const int wm = (wave >> 1) * 64, wn = (wave & 1) * 64;
  const int t = lane & 15, quad = lane >> 4, kq = quad * 8;

  f32x4 acc[4][4];
#pragma unroll
  for (int i = 0; i < 4; i++)
#pragma unroll
    for (int j = 0; j < 4; j++) acc[i][j] = (f32x4){0.f, 0.f, 0.f, 0.f};

  const int srow = tid >> 2;            // staging row (0..63), 2 r-iters
  const int skc  = (tid & 3) * 8;       // staging k offset (elements)
  const size_t arow_off = (size_t)(m0 + srow) * K + skc;
  const size_t brow_off = (size_t)(n0 + srow) * K + skc;

  auto stage = [&](int k0, int buf) {
#pragma unroll
    for (int r = 0; r < 2; ++r) {
      size_t aoff = arow_off + (size_t)(r * 64) * K + k0;
      size_t boff = brow_off + (size_t)(r * 64) * K + k0;
      int ld = r * 4096 + tid * 16;     // byte offset within an 8 KB plane
      GLD16(A + aoff, (char*)&sA[buf][0] + ld);
      GLD16(B + boff, (char*)&sB[buf][0] + ld);
    }
  };

  // prologue: stage tile 0, publish
  stage(0, 0);
  __syncthreads();

  constexpr int NSTEP = K / 32;
#pragma unroll
  for (int it = 0; it < NSTEP; ++it) {
    const int cur = it & 1, nxt = cur ^ 1;
    if (it + 1 < NSTEP) stage((it + 1) * 32, nxt);   // async into other buffer

    f16x8 a[4], b[4];
#pragma unroll
    for (int i = 0; i < 4; ++i) {
      a[i] = *(const f16x8*)&sA[cur][(wm + t + i * 16) * 32 + kq];
      b[i] = *(const f16x8*)&sB[cur][(wn + t + i * 16) * 32 + kq];
    }
#pragma unroll
    for (int i = 0; i < 4; ++i)
#pragma unroll
      for (int j = 0; j < 4; ++j)
        acc[i][j] = __builtin_amdgcn_mfma_f32_16x16x32_f16(a[i], b[j], acc[i][j], 0, 0, 0);

    __syncthreads();   // publishes tile it+1; also fences buf reuse
  }

  // ---- att partials: per-row dot with att vectors, from fp32 accs ----
  const float* asv = att_s + hb * CH;
  const float* adv = att_d + hb * CH;
#pragma unroll
  for (int i = 0; i < 4; ++i) {
    float sa[4] = {0.f, 0.f, 0.f, 0.f}, sd[4] = {0.f, 0.f, 0.f, 0.f};
#pragma unroll
    for (int j = 0; j < 4; ++j) {
      int c = wn + j * 16 + t;
      float sc = asv[c], dc = adv[c];
#pragma unroll
      for (int r = 0; r < 4; ++r) {
        sa[r] = fmaf(acc[i][j][r], sc, sa[r]);
        sd[r] = fmaf(acc[i][j][r], dc, sd[r]);
      }
    }
#pragma unroll
    for (int r = 0; r < 4; ++r) {
#pragma unroll
      for (int mask = 1; mask < 16; mask <<= 1) {
        sa[r] += __shfl_xor(sa[r], mask, 64);
        sd[r] += __shfl_xor(sd[r], mask, 64);
      }
      if (t == 0) {
        sAtt[0][wave][i * 16 + quad * 4 + r] = sa[r];
        sAtt[1][wave][i * 16 + quad * 4 + r] = sd[r];
      }
    }
  }

  // ---- C stores (scalar fp16; 16 consecutive lanes write 32 B contiguous) ----
#pragma unroll
  for (int i = 0; i < 4; ++i)
#pragma unroll
    for (int j = 0; j < 4; ++j)
#pragma unroll
      for (int r = 0; r < 4; ++r) {
        int m = m0 + wm + i * 16 + quad * 4 + r;
        int n = n0 + wn + j * 16 + t;
        C[(size_t)m * NOUT + n] = __float2half(acc[i][j][r]);
      }

  __syncthreads();   // sAtt complete
  // ---- att finals: combine the two col-waves of each row-half ----
  if ((wave & 1) == 0) {
    int gm = m0 + (wave >> 1) * 64 + lane;
    if (gm < N_NODES) {
      as_[gm * HEADS + hb] = sAtt[0][wave][lane] + sAtt[0][wave + 1][lane];
      ad_[gm * HEADS + hb] = sAtt[1][wave][lane] + sAtt[1][wave + 1][lane];
    }
  }
}

// ---------------- GAT aggregation, fp16 gather ----------------
// one wave per dst node. lane -> (h, 8 channels) => one 16 B load per edge.
// No explicit segment-max (|alpha|max ~ 8 << 88, algebraically identical).
// HALF_OUT=1: fp16 out (feeds layer-2 GEMM directly). HALF_OUT=0: fp32 out.

template <bool HALF_OUT>
__global__ __launch_bounds__(256) void gat_aggregate_f16(const __half* __restrict__ xh,
                                                         const float* __restrict__ as_,
                                                         const float* __restrict__ ad_,
                                                         const int* __restrict__ row_ptr,
                                                         const int* __restrict__ col,
                                                         const float* __restrict__ bias,
                                                         void* __restrict__ outv) {
  int node = (blockIdx.x * 256 + threadIdx.x) >> 6;
  if (node >= N_NODES) return;
  int lane = threadIdx.x & 63;
  int h = lane >> 4, ls = lane & 15, cb = ls * 8;
  int s = row_ptr[node], e = row_ptr[node + 1];
  float adh = ad_[node * HEADS + h];

  float acc[8];
#pragma unroll
  for (int j = 0; j < 8; j++) acc[j] = 0.f;
  float denom = 0.f;

  auto accum = [&](uint4 q, float w) {
    __half2 q0 = *(__half2*)&q.x, q1 = *(__half2*)&q.y;
    __half2 q2 = *(__half2*)&q.z, q3 = *(__half2*)&q.w;
    float2 f0 = __half22float2(q0), f1 = __half22float2(q1);
    float2 f2 = __half22float2(q2), f3 = __half22float2(q3);
    acc[0] = fmaf(w, f0.x, acc[0]); acc[1] = fmaf(w, f0.y, acc[1]);
    acc[2] = fmaf(w, f1.x, acc[2]); acc[3] = fmaf(w, f1.y, acc[3]);
    acc[4] = fmaf(w, f2.x, acc[4]); acc[5] = fmaf(w, f2.y, acc[5]);
    acc[6] = fmaf(w, f3.x, acc[6]); acc[7] = fmaf(w, f3.y, acc[7]);
  };

  int i = s;
  for (; i + 4 <= e; i += 4) {
    int s0 = col[i], s1 = col[i + 1], s2 = col[i + 2], s3 = col[i + 3];
    float l0 = as_[s0 * HEADS + h];
    float l1 = as_[s1 * HEADS + h];
    float l2 = as_[s2 * HEADS + h];
    float l3 = as_[s3 * HEADS + h];
    uint4 q0 = *(const uint4*)(xh + (size_t)s0 * NOUT + h * CH + cb);
    uint4 q1 = *(const uint4*)(xh + (size_t)s1 * NOUT + h * CH + cb);
    uint4 q2 = *(const uint4*)(xh + (size_t)s2 * NOUT + h * CH + cb);
    uint4 q3 = *(const uint4*)(xh + (size_t)s3 * NOUT + h * CH + cb);
    float a0 = l0 + adh; a0 = (a0 >= 0.f) ? a0 : NEG_SLOPE * a0;
    float a1 = l1 + adh; a1 = (a1 >= 0.f) ? a1 : NEG_SLOPE * a1;
    float a2 = l2 + adh; a2 = (a2 >= 0.f) ? a2 : NEG_SLOPE * a2;
    float a3 = l3 + adh; a3 = (a3 >= 0.f) ? a3 : NEG_SLOPE * a3;
    float w0 = __expf(a0), w1 = __expf(a1), w2 = __expf(a2), w3 = __expf(a3);
    denom += (w0 + w1) + (w2 + w3);
    accum(q0, w0); accum(q1, w1); accum(q2, w2); accum(q3, w3);
  }
  for (; i < e; ++i) {
    int src = col[i];
    float l = as_[src * HEADS + h];
    uint4 q = *(const uint4*)(xh + (size_t)src * NOUT + h * CH + cb);
    float a = l + adh; a = (a >= 0.f) ? a : NEG_SLOPE * a;
    float w = __expf(a);
    denom += w;
    accum(q, w);
  }

  float inv = 1.f / (denom + 1e-16f);
#pragma unroll
  for (int j = 0; j < 8; j++) acc[j] *= inv;

  // mean over heads: butterfly over lane bits 4,5
#pragma unroll
  for (int j = 0; j < 8; j++) {
    acc[j] += __shfl_xor(acc[j], 16, 64);
    acc[j] += __shfl_xor(acc[j], 32, 64);
  }
  if (h == 0) {
    float r[8];
#pragma unroll
    for (int j = 0; j < 8; j++) r[j] = acc[j] * 0.25f + bias[cb + j];
    if (HALF_OUT) {
      __half2 o[4];
#pragma unroll
      for (int j = 0; j < 4; j++)
        o[j] = __float22half2_rn(make_float2(r[2 * j], r[2 * j + 1]));
      *(uint4*)((__half*)outv + (size_t)node * CH + cb) = *(uint4*)o;
    } else {
      float4 o0 = make_float4(r[0], r[1], r[2], r[3]);
      float4 o1 = make_float4(r[4], r[5], r[6], r[7]);
      *(float4*)((float*)outv + (size_t)node * CH + cb)     = o0;
      *(float4*)((float*)outv + (size_t)node * CH + cb + 4) = o1;
    }
  }
}

// ---------------- launch ----------------

extern "C" void kernel_launch(void* const* d_in, const int* in_sizes, int n_in,
                              void* d_out, int out_size, void* d_ws, size_t ws_size,
                              hipStream_t stream) {
  const float* x      = (const float*)d_in[0];
  const int*   ei     = (const int*)  d_in[1];
  const float* W1     = (const float*)d_in[2];
  const float* att_s1 = (const float*)d_in[3];
  const float* att_d1 = (const float*)d_in[4];
  const float* b1     = (const float*)d_in[5];
  const float* W2     = (const float*)d_in[6];
  const float* att_s2 = (const float*)d_in[7];
  const float* att_d2 = (const float*)d_in[8];
  const float* b2     = (const float*)d_in[9];
  float* out = (float*)d_out;

  char* ws = (char*)d_ws;
  size_t off = 0;
  auto alloc = [&](size_t bytes) -> void* {
    void* p = ws + off;
    off += (bytes + 255) & ~(size_t)255;
    return p;
  };
  __half* A1_16  = (__half*)alloc((size_t)MP * 256 * 2);   // 25.6 MB (x in fp16)
  __half* A2_16  = (__half*)alloc((size_t)MP * 128 * 2);   // 12.8 MB (layer-1 agg out)
  __half* B1_16  = (__half*)alloc((size_t)512 * 256 * 2);
  __half* B2_16  = (__half*)alloc((size_t)512 * 128 * 2);
  __half* xh16   = (__half*)alloc((size_t)MP * NOUT * 2);  // 51.2 MB
  float* as_     = (float*)alloc((size_t)N_NODES * HEADS * 4);
  float* ad_     = (float*)alloc((size_t)N_NODES * HEADS * 4);
  int*   row_ptr = (int*)alloc((size_t)(N_NODES + 1) * 4);
  int*   deg     = (int*)alloc((size_t)N_NODES * 4);       // deg+cursor adjacent:
  int*   cursor  = (int*)alloc((size_t)N_NODES * 4);       // one memset covers both
  int*   col     = (int*)alloc((size_t)E_TOT * 4);

  const int edge_blocks = (E_TOT + 255) / 256;
  const int node_wave_blocks = (N_NODES + 3) / 4;
  dim3 ggrid(MP / 128, HEADS);   // 391 x 4

  // CSR build (by dst); deg and cursor zeroed in one memset
  hipMemsetAsync(deg, 0, (size_t)N_NODES * 2 * 4 + 256, stream);
  count_deg<<<edge_blocks, 256, 0, stream>>>(ei, deg);
  scan_deg_fast<<<1, 1024, 0, stream>>>(deg, row_ptr);
  scatter_edges<<<edge_blocks, 256, 0, stream>>>(ei, row_ptr, cursor, col);

  // cast x, W1, W2 to fp16 in one pass
  cvt_all_f16<<<(CVT_N2 + 255) / 256, 256, 0, stream>>>(x, A1_16, W1, B1_16, W2, B2_16);

  // layer 1
  gemm_att<256><<<ggrid, 256, 0, stream>>>(A1_16, B1_16, att_s1, att_d1,
                                           xh16, as_, ad_);
  gat_aggregate_f16<true><<<node_wave_blocks, 256, 0, stream>>>(
      xh16, as_, ad_, row_ptr, col, b1, A2_16);

  // layer 2 (A = fp16 output of aggregate-1)
  gemm_att<128><<<ggrid, 256, 0, stream>>>(A2_16, B2_16, att_s2, att_d2,
                                           xh16, as_, ad_);
  gat_aggregate_f16<false><<<node_wave_blocks, 256, 0, stream>>>(
      xh16, as_, ad_, row_ptr, col, b2, out);
}

// Round 8
// 596.550 us; speedup vs baseline: 1.0356x; 1.0356x over previous
//
#include <hip/hip_runtime.h>
#include <hip/hip_fp16.h>
#include <math.h>

#define N_NODES 50000
#define MP      50048              /* padded rows = 391*128 */
#define N_EDGES 800000
#define E_TOT   (N_EDGES + N_NODES)
#define EB      ((E_TOT + 255) / 256)   /* 3321 edge blocks in prep */
#define HEADS   4
#define CH      128
#define NOUT    512
#define NEG_SLOPE 0.2f

typedef unsigned int u32;
typedef unsigned short u16;
typedef __attribute__((ext_vector_type(8))) _Float16 f16x8;
typedef __attribute__((ext_vector_type(4))) float f32x4;

// ---------------- prep: edge-degree count + W1/W2 fp32->fp16 cast ----------------

__global__ __launch_bounds__(256) void prep(const int* __restrict__ ei,
                                            int* __restrict__ deg,
                                            const float* __restrict__ W1,
                                            __half* __restrict__ B1,
                                            const float* __restrict__ W2,
                                            __half* __restrict__ B2) {
  int b = blockIdx.x, tid = threadIdx.x;
  if (b < EB) {
    int e = b * 256 + tid;
    if (e < E_TOT) {
      int dst = (e < N_EDGES) ? ei[N_EDGES + e] : (e - N_EDGES);
      atomicAdd(&deg[dst], 1);
    }
    return;
  }
  const float* s; __half* d; int k;
  if (b < EB + 128) { s = W1; d = B1; k = (b - EB) * 256 + tid; }        // 32768 float4
  else              { s = W2; d = B2; k = (b - EB - 128) * 256 + tid; }  // 16384 float4
  float4 v = ((const float4*)s)[k];
  __half2 h01 = __float22half2_rn(make_float2(v.x, v.y));
  __half2 h23 = __float22half2_rn(make_float2(v.z, v.w));
  uint2 pk = make_uint2(*(u32*)&h01, *(u32*)&h23);
  ((uint2*)d)[k] = pk;
}

// single block, 1024 threads: per-thread sequential chunk + one 1024-wide scan
__global__ __launch_bounds__(1024) void scan_deg_fast(const int* __restrict__ deg,
                                                      int* __restrict__ row_ptr) {
  __shared__ int ssum[1024];
  const int tid = threadIdx.x;
  const int CHUNK = (N_NODES + 1023) / 1024;   // 49
  const int base = tid * CHUNK;
  int s = 0;
  for (int i = 0; i < CHUNK; ++i) {
    int idx = base + i;
    if (idx < N_NODES) s += deg[idx];
  }
  ssum[tid] = s;
  __syncthreads();
  for (int off = 1; off < 1024; off <<= 1) {
    int v = (tid >= off) ? ssum[tid - off] : 0;
    __syncthreads();
    ssum[tid] += v;
    __syncthreads();
  }
  int run = (tid > 0) ? ssum[tid - 1] : 0;
  for (int i = 0; i < CHUNK; ++i) {
    int idx = base + i;
    if (idx < N_NODES) { run += deg[idx]; row_ptr[idx + 1] = run; }
  }
  if (tid == 0) row_ptr[0] = 0;
}

__global__ __launch_bounds__(256) void scatter_edges(const int* __restrict__ ei,
                                                     const int* __restrict__ row_ptr,
                                                     int* __restrict__ cursor,
                                                     int* __restrict__ col) {
  int e = blockIdx.x * 256 + threadIdx.x;
  if (e >= E_TOT) return;
  int src, dst;
  if (e < N_EDGES) { src = ei[e]; dst = ei[N_EDGES + e]; }
  else             { src = e - N_EDGES; dst = src; }
  int pos = atomicAdd(&cursor[dst], 1);
  col[row_ptr[dst] + pos] = src;
}

// ---------------- fp16 MFMA GEMM (head-pair blocks) + fused attention epilogue ----
// C_fp16[MP,512] = A[M,K] @ B_fp16[512,K]^T, fp32 accumulate.
// Grid (MP/128, 2): block = 128 rows x 256 cols (one HEAD PAIR) x 512 threads.
// A staged 2x total (vs 4x with per-head blocks): -75 MB staged bytes.
// AF32: stage A as raw fp32 (direct from input x, no cvt pass), convert to
// fp16 in the LDS->frag path (RNE). Rows clamped to N_NODES-1 (input is
// exact-sized; pad rows produce garbage only in C pad rows, never read).
// K-loop: r6-style single-buffer, 2 barriers/step, GLD16 staging (dbuf was
// neutral in r7 -> staging-byte-bound, not latency-bound).
// Epilogue: per-row <xh,att_s/d> from fp32 accs (replaces node_att).

#define GLD16(gp, lp)                                                          \
  __builtin_amdgcn_global_load_lds(                                            \
      (const __attribute__((address_space(1))) u32*)(gp),                      \
      (__attribute__((address_space(3))) u32*)(lp), 16, 0, 0)

template <int K, bool AF32>
__global__ __launch_bounds__(512) void gemm_att(
    const void* __restrict__ Ap, const __half* __restrict__ B,
    const float* __restrict__ att_s, const float* __restrict__ att_d,
    __half* __restrict__ C, float* __restrict__ as_, float* __restrict__ ad_) {
  constexpr int AESZ = AF32 ? 4 : 2;
  __shared__ char sAraw[128 * 32 * AESZ];   // 16 KB (fp32) or 8 KB (fp16)
  __shared__ u16  sB[256 * 32];             // 16 KB
  __shared__ float sAtt[2][8][64];          // 4 KB
  const int tid  = threadIdx.x;             // 0..511
  const int lane = tid & 63;
  const int wave = tid >> 6;                // 0..7
  const int m0 = blockIdx.x * 128;
  const int hb = blockIdx.y;                // head pair: cols hb*256..hb*256+255
  const int n0 = hb * 256;
  const int wm = (wave >> 2) * 64;          // row half
  const int wn = (wave & 3) * 64;           // col quarter
  const int t = lane & 15, quad = lane >> 4;

  f32x4 acc[4][4];
#pragma unroll
  for (int i = 0; i < 4; i++)
#pragma unroll
    for (int j = 0; j < 4; j++) acc[i][j] = (f32x4){0.f, 0.f, 0.f, 0.f};

  constexpr int ACH  = 128 * 32 * AESZ / 16;   // A 16B-chunks per step (512 or 1024)
  constexpr int ACPR = 32 * AESZ / 16;         // A chunks per row (4 or 8)

  for (int k0 = 0; k0 < K; k0 += 32) {
    __syncthreads();
    // ---- stage A ----
#pragma unroll
    for (int r = 0; r < ACH / 512; ++r) {
      int c = tid + r * 512;
      int row = c / ACPR, w16 = c % ACPR;
      int grow = m0 + row;
      if (grow > N_NODES - 1) grow = N_NODES - 1;     // input x is exact-sized
      const char* gp = (const char*)Ap + ((size_t)grow * K + k0) * AESZ + w16 * 16;
      GLD16(gp, sAraw + c * 16);
    }
    // ---- stage B (256 rows x 32 k fp16 = 16 KB) ----
#pragma unroll
    for (int r = 0; r < 2; ++r) {
      int c = tid + r * 512;
      int row = c >> 2, w16 = c & 3;
      const char* gp = (const char*)B + ((size_t)(n0 + row) * K + k0) * 2 + w16 * 16;
      GLD16(gp, (char*)sB + c * 16);
    }
    __syncthreads();

    f16x8 a[4], b[4];
#pragma unroll
    for (int i = 0; i < 4; ++i) {
      int ar = wm + t + i * 16;
      if (AF32) {
        const float* fp = (const float*)sAraw + ar * 32 + quad * 8;
        f32x4 lo = *(const f32x4*)fp;
        f32x4 hi = *(const f32x4*)(fp + 4);
        f16x8 v;
#pragma unroll
        for (int e2 = 0; e2 < 4; ++e2) {
          v[e2]     = (_Float16)lo[e2];
          v[e2 + 4] = (_Float16)hi[e2];
        }
        a[i] = v;
      } else {
        a[i] = *(const f16x8*)((const u16*)sAraw + ar * 32 + quad * 8);
      }
      b[i] = *(const f16x8*)&sB[(wn + t + i * 16) * 32 + quad * 8];
    }
#pragma unroll
    for (int i = 0; i < 4; ++i)
#pragma unroll
      for (int j = 0; j < 4; ++j)
        acc[i][j] = __builtin_amdgcn_mfma_f32_16x16x32_f16(a[i], b[j], acc[i][j], 0, 0, 0);
  }

  // ---- att partials: per-row dot with att vectors (head fixed per wave) ----
  const int hloc = wn >> 7;                    // 0/1 within the pair
  const float* asv = att_s + (hb * 2 + hloc) * CH + (wn & 127);
  const float* adv = att_d + (hb * 2 + hloc) * CH + (wn & 127);
#pragma unroll
  for (int i = 0; i < 4; ++i) {
    float sa[4] = {0.f, 0.f, 0.f, 0.f}, sd[4] = {0.f, 0.f, 0.f, 0.f};
#pragma unroll
    for (int j = 0; j < 4; ++j) {
      int c = j * 16 + t;
      float sc = asv[c], dc = adv[c];
#pragma unroll
      for (int r = 0; r < 4; ++r) {
        sa[r] = fmaf(acc[i][j][r], sc, sa[r]);
        sd[r] = fmaf(acc[i][j][r], dc, sd[r]);
      }
    }
#pragma unroll
    for (int r = 0; r < 4; ++r) {
#pragma unroll
      for (int mask = 1; mask < 16; mask <<= 1) {
        sa[r] += __shfl_xor(sa[r], mask, 64);
        sd[r] += __shfl_xor(sd[r], mask, 64);
      }
      if (t == 0) {
        sAtt[0][wave][i * 16 + quad * 4 + r] = sa[r];
        sAtt[1][wave][i * 16 + quad * 4 + r] = sd[r];
      }
    }
  }

  // ---- C stores (C/D layout col=lane&15, row=quad*4+reg) ----
#pragma unroll
  for (int i = 0; i < 4; ++i)
#pragma unroll
    for (int j = 0; j < 4; ++j)
#pragma unroll
      for (int r = 0; r < 4; ++r) {
        int m = m0 + wm + i * 16 + quad * 4 + r;
        int n = n0 + wn + j * 16 + t;
        C[(size_t)m * NOUT + n] = __float2half(acc[i][j][r]);
      }

  __syncthreads();   // sAtt complete
  // ---- att finals: combine the two col-waves of each (row-half, head) ----
  if ((wave & 1) == 0) {
    int gm = m0 + (wave >> 2) * 64 + lane;
    int h = hb * 2 + ((wave >> 1) & 1);
    if (gm < N_NODES) {
      as_[gm * HEADS + h] = sAtt[0][wave][lane] + sAtt[0][wave + 1][lane];
      ad_[gm * HEADS + h] = sAtt[1][wave][lane] + sAtt[1][wave + 1][lane];
    }
  }
}

// ---------------- GAT aggregation, fp16 gather ----------------
// one wave per dst node. lane -> (h, 8 channels) => one coalesced 1KB row read
// per edge per wave. At the measured ~11 B/cyc/CU L1-miss service ceiling.
// No explicit segment-max (|alpha|max ~ 8 << 88, algebraically identical).
// HALF_OUT=1: fp16 out (feeds layer-2 GEMM directly). HALF_OUT=0: fp32 out.

template <bool HALF_OUT>
__global__ __launch_bounds__(256) void gat_aggregate_f16(const __half* __restrict__ xh,
                                                         const float* __restrict__ as_,
                                                         const float* __restrict__ ad_,
                                                         const int* __restrict__ row_ptr,
                                                         const int* __restrict__ col,
                                                         const float* __restrict__ bias,
                                                         void* __restrict__ outv) {
  int node = (blockIdx.x * 256 + threadIdx.x) >> 6;
  if (node >= N_NODES) return;
  int lane = threadIdx.x & 63;
  int h = lane >> 4, ls = lane & 15, cb = ls * 8;
  int s = row_ptr[node], e = row_ptr[node + 1];
  float adh = ad_[node * HEADS + h];

  float acc[8];
#pragma unroll
  for (int j = 0; j < 8; j++) acc[j] = 0.f;
  float denom = 0.f;

  auto accum = [&](uint4 q, float w) {
    __half2 q0 = *(__half2*)&q.x, q1 = *(__half2*)&q.y;
    __half2 q2 = *(__half2*)&q.z, q3 = *(__half2*)&q.w;
    float2 f0 = __half22float2(q0), f1 = __half22float2(q1);
    float2 f2 = __half22float2(q2), f3 = __half22float2(q3);
    acc[0] = fmaf(w, f0.x, acc[0]); acc[1] = fmaf(w, f0.y, acc[1]);
    acc[2] = fmaf(w, f1.x, acc[2]); acc[3] = fmaf(w, f1.y, acc[3]);
    acc[4] = fmaf(w, f2.x, acc[4]); acc[5] = fmaf(w, f2.y, acc[5]);
    acc[6] = fmaf(w, f3.x, acc[6]); acc[7] = fmaf(w, f3.y, acc[7]);
  };

  int i = s;
  for (; i + 4 <= e; i += 4) {
    int s0 = col[i], s1 = col[i + 1], s2 = col[i + 2], s3 = col[i + 3];
    float l0 = as_[s0 * HEADS + h];
    float l1 = as_[s1 * HEADS + h];
    float l2 = as_[s2 * HEADS + h];
    float l3 = as_[s3 * HEADS + h];
    uint4 q0 = *(const uint4*)(xh + (size_t)s0 * NOUT + h * CH + cb);
    uint4 q1 = *(const uint4*)(xh + (size_t)s1 * NOUT + h * CH + cb);
    uint4 q2 = *(const uint4*)(xh + (size_t)s2 * NOUT + h * CH + cb);
    uint4 q3 = *(const uint4*)(xh + (size_t)s3 * NOUT + h * CH + cb);
    float a0 = l0 + adh; a0 = (a0 >= 0.f) ? a0 : NEG_SLOPE * a0;
    float a1 = l1 + adh; a1 = (a1 >= 0.f) ? a1 : NEG_SLOPE * a1;
    float a2 = l2 + adh; a2 = (a2 >= 0.f) ? a2 : NEG_SLOPE * a2;
    float a3 = l3 + adh; a3 = (a3 >= 0.f) ? a3 : NEG_SLOPE * a3;
    float w0 = __expf(a0), w1 = __expf(a1), w2 = __expf(a2), w3 = __expf(a3);
    denom += (w0 + w1) + (w2 + w3);
    accum(q0, w0); accum(q1, w1); accum(q2, w2); accum(q3, w3);
  }
  for (; i < e; ++i) {
    int src = col[i];
    float l = as_[src * HEADS + h];
    uint4 q = *(const uint4*)(xh + (size_t)src * NOUT + h * CH + cb);
    float a = l + adh; a = (a >= 0.f) ? a : NEG_SLOPE * a;
    float w = __expf(a);
    denom += w;
    accum(q, w);
  }

  float inv = 1.f / (denom + 1e-16f);
#pragma unroll
  for (int j = 0; j < 8; j++) acc[j] *= inv;

  // mean over heads: butterfly over lane bits 4,5
#pragma unroll
  for (int j = 0; j < 8; j++) {
    acc[j] += __shfl_xor(acc[j], 16, 64);
    acc[j] += __shfl_xor(acc[j], 32, 64);
  }
  if (h == 0) {
    float r[8];
#pragma unroll
    for (int j = 0; j < 8; j++) r[j] = acc[j] * 0.25f + bias[cb + j];
    if (HALF_OUT) {
      __half2 o[4];
#pragma unroll
      for (int j = 0; j < 4; j++)
        o[j] = __float22half2_rn(make_float2(r[2 * j], r[2 * j + 1]));
      *(uint4*)((__half*)outv + (size_t)node * CH + cb) = *(uint4*)o;
    } else {
      float4 o0 = make_float4(r[0], r[1], r[2], r[3]);
      float4 o1 = make_float4(r[4], r[5], r[6], r[7]);
      *(float4*)((float*)outv + (size_t)node * CH + cb)     = o0;
      *(float4*)((float*)outv + (size_t)node * CH + cb + 4) = o1;
    }
  }
}

// ---------------- launch ----------------

extern "C" void kernel_launch(void* const* d_in, const int* in_sizes, int n_in,
                              void* d_out, int out_size, void* d_ws, size_t ws_size,
                              hipStream_t stream) {
  const float* x      = (const float*)d_in[0];
  const int*   ei     = (const int*)  d_in[1];
  const float* W1     = (const float*)d_in[2];
  const float* att_s1 = (const float*)d_in[3];
  const float* att_d1 = (const float*)d_in[4];
  const float* b1     = (const float*)d_in[5];
  const float* W2     = (const float*)d_in[6];
  const float* att_s2 = (const float*)d_in[7];
  const float* att_d2 = (const float*)d_in[8];
  const float* b2     = (const float*)d_in[9];
  float* out = (float*)d_out;

  char* ws = (char*)d_ws;
  size_t off = 0;
  auto alloc = [&](size_t bytes) -> void* {
    void* p = ws + off;
    off += (bytes + 255) & ~(size_t)255;
    return p;
  };
  __half* A2_16  = (__half*)alloc((size_t)MP * 128 * 2);   // 12.8 MB (layer-1 agg out)
  __half* B1_16  = (__half*)alloc((size_t)512 * 256 * 2);
  __half* B2_16  = (__half*)alloc((size_t)512 * 128 * 2);
  __half* xh16   = (__half*)alloc((size_t)MP * NOUT * 2);  // 51.2 MB
  float* as_     = (float*)alloc((size_t)N_NODES * HEADS * 4);
  float* ad_     = (float*)alloc((size_t)N_NODES * HEADS * 4);
  int*   row_ptr = (int*)alloc((size_t)(N_NODES + 1) * 4);
  int*   deg     = (int*)alloc((size_t)N_NODES * 4);       // deg+cursor adjacent:
  int*   cursor  = (int*)alloc((size_t)N_NODES * 4);       // one memset covers both
  int*   col     = (int*)alloc((size_t)E_TOT * 4);

  const int edge_blocks = (E_TOT + 255) / 256;
  const int node_wave_blocks = (N_NODES + 3) / 4;
  dim3 ggrid(MP / 128, 2);   // 391 x 2 head-pair blocks

  // CSR count + W casts fused; deg and cursor zeroed in one memset
  hipMemsetAsync(deg, 0, (size_t)N_NODES * 2 * 4 + 256, stream);
  prep<<<EB + 192, 256, 0, stream>>>(ei, deg, W1, B1_16, W2, B2_16);
  scan_deg_fast<<<1, 1024, 0, stream>>>(deg, row_ptr);
  scatter_edges<<<edge_blocks, 256, 0, stream>>>(ei, row_ptr, cursor, col);

  // layer 1 (A = raw fp32 x, converted in-kernel)
  gemm_att<256, true><<<ggrid, 512, 0, stream>>>(x, B1_16, att_s1, att_d1,
                                                 xh16, as_, ad_);
  gat_aggregate_f16<true><<<node_wave_blocks, 256, 0, stream>>>(
      xh16, as_, ad_, row_ptr, col, b1, A2_16);

  // layer 2 (A = fp16 output of aggregate-1)
  gemm_att<128, false><<<ggrid, 512, 0, stream>>>(A2_16, B2_16, att_s2, att_d2,
                                                  xh16, as_, ad_);
  gat_aggregate_f16<false><<<node_wave_blocks, 256, 0, stream>>>(
      xh16, as_, ad_, row_ptr, col, b2, out);
}